// Round 1
// 73.093 us; speedup vs baseline: 1.0045x; 1.0045x over previous
//
#include <hip/hip_runtime.h>
#include <math.h>

// Problem constants (fixed by the reference).
#define BB 128
#define II 256
#define OO 4096
#define DECAY 0.95f

constexpr int TB = 16;   // bi rows per block (4 per wave)
constexpr int TO = 32;   // o cols per block (one per lane-pair; i-split across half-waves)
constexpr int QC = 64;   // stim cols staged per quarter
constexpr int SP = QC + 4;  // stim row stride: 68 ≡ 4 (mod 32 banks) ->
                            // each 8-lane b128 phase covers all 32 banks

// LDS: stim 2*32*68*4 = 17408 B (double-buffered quarter tiles)
//      x    16*256*4  = 16384 B (whole x tile, broadcast reads)
//      total 33792 B -> 4 blocks/CU; grid 1024 = 4/CU exactly -> 4 waves/SIMD
__global__ __launch_bounds__(256, 4) void stimulus_linf_kernel(
    const float* __restrict__ x,     // (B, I)
    const float* __restrict__ stim,  // (O, I)
    const float* __restrict__ a,     // (O,)
    const float* __restrict__ b,     // (O,)
    const float* __restrict__ state, // (B, O)
    float* __restrict__ out)         // (B, O)
{
    __shared__ float s_stim[2][TO][SP];
    __shared__ float s_x[TB][II];

    const int tid  = threadIdx.x;
    const int lane = tid & 63;
    const int wave = tid >> 6;
    const int ol   = lane & 31;   // o index within tile
    const int h2   = lane >> 5;   // which 32-col half of each staged quarter

    // blocks sharing a stim tile sit 128 apart -> same XCD (128 % 8 == 0)
    const int o_tile  = blockIdx.x & 127;
    const int bi_tile = blockIdx.x >> 7;
    const int o_base  = o_tile * TO;
    const int bi_base = bi_tile * TB;

    // ---- epilogue prefetch: issue now, consume at the end ----
    const int o  = o_base + ol;
    const float av = a[o];
    const float bv = b[o];
    const int r0 = h2 * 2;  // each half-wave owns 2 of the wave's 4 rows for I/O
    const float st0 = state[(bi_base + wave * 4 + r0    ) * OO + o];
    const float st1 = state[(bi_base + wave * 4 + r0 + 1) * OO + o];

    // ---- stage x tile once: 16 rows x 256 cols, 4 float4 per thread ----
    #pragma unroll
    for (int k = 0; k < 4; ++k) {
        const int idx = tid + k * 256;
        const int row = idx >> 6;          // 64 float4 per row
        const int c4  = (idx & 63) * 4;
        *reinterpret_cast<float4*>(&s_x[row][c4]) =
            *reinterpret_cast<const float4*>(&x[(bi_base + row) * II + c4]);
    }

    // stage stim quarter q (cols [q*64, q*64+64)) into buffer bq:
    // 512 float4, 2 per thread, issued back-to-back.
    auto stage = [&](int q, int bq) {
        #pragma unroll
        for (int k = 0; k < 2; ++k) {
            const int idx = tid + k * 256;
            const int row = idx >> 4;      // 16 float4 per quarter-row
            const int c4  = (idx & 15) * 4;
            *reinterpret_cast<float4*>(&s_stim[bq][row][c4]) =
                *reinterpret_cast<const float4*>(
                    &stim[(o_base + row) * II + q * QC + c4]);
        }
    };

    float d[4] = {0.f, 0.f, 0.f, 0.f};  // |.| >= 0 so 0-init is exact

    // compute quarter q from buffer bq: each lane does its 32-col half.
    auto compute = [&](int q, int bq) {
        const int cbase = h2 * 32;
        const int xbase = q * QC + cbase;
        #pragma unroll 4
        for (int i4 = 0; i4 < 8; ++i4) {
            const float4 s4 = *reinterpret_cast<const float4*>(
                &s_stim[bq][ol][cbase + i4 * 4]);
            // uniform-per-half-wave LDS broadcasts (2-way: free)
            const float4 xv0 = *reinterpret_cast<const float4*>(
                &s_x[wave * 4 + 0][xbase + i4 * 4]);
            const float4 xv1 = *reinterpret_cast<const float4*>(
                &s_x[wave * 4 + 1][xbase + i4 * 4]);
            const float4 xv2 = *reinterpret_cast<const float4*>(
                &s_x[wave * 4 + 2][xbase + i4 * 4]);
            const float4 xv3 = *reinterpret_cast<const float4*>(
                &s_x[wave * 4 + 3][xbase + i4 * 4]);
            d[0] = fmaxf(fmaxf(d[0], fabsf(xv0.x - s4.x)), fabsf(xv0.y - s4.y));
            d[0] = fmaxf(fmaxf(d[0], fabsf(xv0.z - s4.z)), fabsf(xv0.w - s4.w));
            d[1] = fmaxf(fmaxf(d[1], fabsf(xv1.x - s4.x)), fabsf(xv1.y - s4.y));
            d[1] = fmaxf(fmaxf(d[1], fabsf(xv1.z - s4.z)), fabsf(xv1.w - s4.w));
            d[2] = fmaxf(fmaxf(d[2], fabsf(xv2.x - s4.x)), fabsf(xv2.y - s4.y));
            d[2] = fmaxf(fmaxf(d[2], fabsf(xv2.z - s4.z)), fabsf(xv2.w - s4.w));
            d[3] = fmaxf(fmaxf(d[3], fabsf(xv3.x - s4.x)), fabsf(xv3.y - s4.y));
            d[3] = fmaxf(fmaxf(d[3], fabsf(xv3.z - s4.z)), fabsf(xv3.w - s4.w));
        }
    };

    // 4-quarter software pipeline: stage(q+1) in flight during compute(q).
    stage(0, 0);
    __syncthreads();
    stage(1, 1);
    compute(0, 0);
    __syncthreads();
    stage(2, 0);
    compute(1, 1);
    __syncthreads();
    stage(3, 1);
    compute(2, 0);
    __syncthreads();
    compute(3, 1);

    // ---- combine the two i-halves (register op, no barrier needed) ----
    #pragma unroll
    for (int r = 0; r < 4; ++r)
        d[r] = fmaxf(d[r], __shfl_xor(d[r], 32, 64));

    // ---- epilogue: each half-wave stores its 2 rows (128B contiguous) ----
    #pragma unroll
    for (int rr = 0; rr < 2; ++rr) {
        const int r   = r0 + rr;
        const int bi  = bi_base + wave * 4 + r;
        const float z   = (av - d[r]) * bv;
        const float val = 1.f / (1.f + __expf(-z));
        const float s   = (rr == 0) ? st0 : st1;
        out[bi * OO + o] = s * DECAY + val;
    }
}

extern "C" void kernel_launch(void* const* d_in, const int* in_sizes, int n_in,
                              void* d_out, int out_size, void* d_ws, size_t ws_size,
                              hipStream_t stream) {
    const float* x     = (const float*)d_in[0];
    const float* stim  = (const float*)d_in[1];
    const float* a     = (const float*)d_in[2];
    const float* b     = (const float*)d_in[3];
    const float* state = (const float*)d_in[4];
    float* out = (float*)d_out;

    const dim3 grid((OO / TO) * (BB / TB));  // 128 * 8 = 1024 blocks = 4/CU
    const dim3 block(256);
    stimulus_linf_kernel<<<grid, block, 0, stream>>>(x, stim, a, b, state, out);
}